// Round 5
// baseline (9607.410 us; speedup 1.0000x reference)
//
#include <hip/hip_runtime.h>

// ResidualVectorQuantizer: B=16, D=512, F=1500, Q=8, C=1024
#define B_ 16
#define D_ 512
#define F_ 1500
#define N_ (B_*F_)   // 24000
#define Q_ 8
#define C_ 1024

constexpr int NBLK = (N_ + 255) / 256;  // 94

// ---------------- init: res2[d][b*F+f] = latents[b][d][f]; zero ssq ----------------
__global__ void k_init(const float* __restrict__ lat, float* __restrict__ res2,
                       double* __restrict__ ssq) {
    int bi = blockIdx.x;            // bi = b*512 + d
    int d = bi & 511, b = bi >> 9;
    const float* src = lat + (size_t)bi * F_;
    float* dst = res2 + (size_t)d * N_ + (size_t)b * F_;
    for (int f = threadIdx.x; f < F_; f += 256) dst[f] = src[f];
    if (bi == 0 && threadIdx.x < Q_) ssq[threadIdx.x] = 0.0;
}

// ---------------- codebook transpose: cbT[q][d][c] = cb[q][c][d] ----------------
__global__ void k_transpose_cb(const float* __restrict__ cb, float* __restrict__ cbT) {
    __shared__ float tile[32][33];
    int bi = blockIdx.x;            // q*512 + cblk*16 + dblk
    int q = bi >> 9;
    int rem = bi & 511;
    int cblk = rem >> 4, dblk = rem & 15;
    int tx = threadIdx.x & 31, ty = threadIdx.x >> 5;  // 32 x 8
    const float* src = cb + ((size_t)q * C_ + (size_t)cblk * 32) * D_ + dblk * 32;
    for (int i = ty; i < 32; i += 8) tile[i][tx] = src[(size_t)i * D_ + tx];
    __syncthreads();
    float* dst = cbT + ((size_t)q * D_ + (size_t)dblk * 32) * C_ + cblk * 32;
    for (int i = ty; i < 32; i += 8) dst[(size_t)i * C_ + tx] = tile[tx][i];
}

// ---------------- H[q*C+c] = np.sum(cb*cb, axis=1) with numpy pairwise fp32 ----------------
__global__ void k_cbnormP(const float* __restrict__ cb, float* __restrict__ Hq) {
#pragma clang fp contract(off)
    int wid = blockIdx.x * 256 + threadIdx.x;   // q*C + c  (0..8191)
    const float* p = cb + (size_t)wid * D_;
    float L[4];
#pragma unroll
    for (int l = 0; l < 4; ++l) {
        const float* pl = p + l * 128;
        float r[8];
#pragma unroll
        for (int j = 0; j < 8; ++j) { float x = pl[j]; r[j] = x * x; }
        for (int i = 8; i < 128; i += 8) {
#pragma unroll
            for (int j = 0; j < 8; ++j) { float x = pl[i + j]; r[j] = r[j] + x * x; }
        }
        L[l] = ((r[0] + r[1]) + (r[2] + r[3])) + ((r[4] + r[5]) + (r[6] + r[7]));
    }
    Hq[wid] = (L[0] + L[1]) + (L[2] + L[3]);
}

// ---------------- S[n] = np.sum(flat*flat, axis=1) with numpy pairwise fp32 ----------------
__global__ void k_rownorm(const float* __restrict__ res2, float* __restrict__ Sn) {
#pragma clang fp contract(off)
    int n = blockIdx.x * 256 + threadIdx.x;
    if (n >= N_) return;
    float L[4];
#pragma unroll
    for (int l = 0; l < 4; ++l) {
        const float* p = res2 + (size_t)(l * 128) * N_ + n;
        float r[8];
#pragma unroll
        for (int j = 0; j < 8; ++j) { float x = p[(size_t)j * N_]; r[j] = x * x; }
        for (int i = 8; i < 128; i += 8) {
#pragma unroll
            for (int j = 0; j < 8; ++j) { float x = p[(size_t)(i + j) * N_]; r[j] = r[j] + x * x; }
        }
        L[l] = ((r[0] + r[1]) + (r[2] + r[3])) + ((r[4] + r[5]) + (r[6] + r[7]));
    }
    Sn[n] = (L[0] + L[1]) + (L[2] + L[3]);
}

// ---------------- distance + argmin, fp32, SINGLE sequential FMA chain k=0..511 ----------------
// A = chain_fma(d=0..511), no kc split (MKL/Eigen-style large-kc model)
// dist = fl32( fl32(S - 2*A) + H ); ties -> lowest index.
// block: 256 threads, 32 rows x full 1024 codewords; per-thread 2 rows x 4 cols.
__global__ __launch_bounds__(256) void k_dist(
        const float* __restrict__ res2, const float* __restrict__ cb,
        const float* __restrict__ Hq, const float* __restrict__ Sn,
        int* __restrict__ codes, int q) {
    __shared__ float xs[32][66];    // [n][d-chunk]
    __shared__ float cs[64][68];    // [c][d-chunk]
    __shared__ float redv[16][32];
    __shared__ int   redi[16][32];

    const int t = threadIdx.x;
    const int n0 = blockIdx.x * 32;
    const int tr = t & 15, tc = t >> 4;
    const float* cbq = cb + (size_t)q * ((size_t)C_ * D_);
    const float* Hqq = Hq + (size_t)q * C_;

    const float S0 = Sn[n0 + 2 * tr];
    const float S1 = Sn[n0 + 2 * tr + 1];

    float bestv0 = 3.4e38f, bestv1 = 3.4e38f;
    int besti0 = 0, besti1 = 0;

    for (int c0 = 0; c0 < C_; c0 += 64) {
        float acc[2][4] = {{0,0,0,0},{0,0,0,0}};

        auto chunk = [&](int dc) {
            __syncthreads();
            {   // stage X: 32 rows x 64 d
                int j = t & 31, dd0 = t >> 5;
#pragma unroll
                for (int k = 0; k < 8; ++k) {
                    int dd = dd0 + 8 * k;
                    xs[j][dd] = res2[(size_t)(dc + dd) * N_ + n0 + j];
                }
            }
            {   // stage CB: 64 rows x 64 d
#pragma unroll
                for (int k = 0; k < 4; ++k) {
                    int idx = t + k * 256;          // 0..1023
                    int r = idx >> 4;               // /16
                    int dcol = (idx & 15) << 2;
                    const float4 v = *(const float4*)(cbq + (size_t)(c0 + r) * D_ + dc + dcol);
                    *(float4*)(&cs[r][dcol]) = v;
                }
            }
            __syncthreads();

            const float2* xp0 = (const float2*)(&xs[2 * tr][0]);
            const float2* xp1 = (const float2*)(&xs[2 * tr + 1][0]);
            const float2* cp0 = (const float2*)(&cs[4 * tc + 0][0]);
            const float2* cp1 = (const float2*)(&cs[4 * tc + 1][0]);
            const float2* cp2 = (const float2*)(&cs[4 * tc + 2][0]);
            const float2* cp3 = (const float2*)(&cs[4 * tc + 3][0]);
#pragma unroll 8
            for (int d2 = 0; d2 < 32; ++d2) {
                const float2 x0 = xp0[d2], x1 = xp1[d2];
                const float2 v0 = cp0[d2], v1 = cp1[d2], v2 = cp2[d2], v3 = cp3[d2];
                // strict d-ascending fused-FMA chain (single accumulator per cell)
                acc[0][0] = fmaf(x0.x, v0.x, acc[0][0]); acc[0][0] = fmaf(x0.y, v0.y, acc[0][0]);
                acc[0][1] = fmaf(x0.x, v1.x, acc[0][1]); acc[0][1] = fmaf(x0.y, v1.y, acc[0][1]);
                acc[0][2] = fmaf(x0.x, v2.x, acc[0][2]); acc[0][2] = fmaf(x0.y, v2.y, acc[0][2]);
                acc[0][3] = fmaf(x0.x, v3.x, acc[0][3]); acc[0][3] = fmaf(x0.y, v3.y, acc[0][3]);
                acc[1][0] = fmaf(x1.x, v0.x, acc[1][0]); acc[1][0] = fmaf(x1.y, v0.y, acc[1][0]);
                acc[1][1] = fmaf(x1.x, v1.x, acc[1][1]); acc[1][1] = fmaf(x1.y, v1.y, acc[1][1]);
                acc[1][2] = fmaf(x1.x, v2.x, acc[1][2]); acc[1][2] = fmaf(x1.y, v2.y, acc[1][2]);
                acc[1][3] = fmaf(x1.x, v3.x, acc[1][3]); acc[1][3] = fmaf(x1.y, v3.y, acc[1][3]);
            }
        };

        // single chain: all 8 chunks into the same accumulators, no join
        chunk(0);   chunk(64);  chunk(128); chunk(192);
        chunk(256); chunk(320); chunk(384); chunk(448);

        {   // dist = fl(fl(S - 2A) + H), fp32, no contraction; ties -> lowest index
#pragma clang fp contract(off)
#pragma unroll
            for (int k = 0; k < 4; ++k) {
                int c = c0 + 4 * tc + k;
                float h = Hqq[c];
                float t0 = S0 - 2.0f * acc[0][k];
                float t1 = S1 - 2.0f * acc[1][k];
                float v0 = t0 + h;
                float v1 = t1 + h;
                if (v0 < bestv0) { bestv0 = v0; besti0 = c; }
                if (v1 < bestv1) { bestv1 = v1; besti1 = c; }
            }
        }
    }

    redv[tc][2 * tr] = bestv0;     redi[tc][2 * tr] = besti0;
    redv[tc][2 * tr + 1] = bestv1; redi[tc][2 * tr + 1] = besti1;
    __syncthreads();
    if (t < 32) {
        float bv = redv[0][t]; int bidx = redi[0][t];
#pragma unroll
        for (int j = 1; j < 16; ++j) {
            float v = redv[j][t]; int ci = redi[j][t];
            if (v < bv || (v == bv && ci < bidx)) { bv = v; bidx = ci; }
        }
        codes[(size_t)q * N_ + n0 + t] = bidx;
    }
}

// ---------------- residual update + per-stage sum of squares ----------------
__global__ void k_update(float* __restrict__ res2, const float* __restrict__ cbT,
                         const int* __restrict__ codes, double* __restrict__ ssq, int q) {
    int bi = blockIdx.x;
    int d = bi / NBLK, nb = bi % NBLK;
    int n = nb * 256 + threadIdx.x;
    double sq = 0.0;
    if (n < N_) {
        int idx = codes[(size_t)q * N_ + n];
        float cv = cbT[((size_t)q * D_ + d) * C_ + idx];
        size_t ri = (size_t)d * N_ + n;
        float r = res2[ri] - cv;
        res2[ri] = r;
        sq = (double)r * (double)r;
    }
#pragma unroll
    for (int off = 32; off; off >>= 1) sq += __shfl_down(sq, off, 64);
    __shared__ double sred[4];
    int lane = threadIdx.x & 63, w = threadIdx.x >> 6;
    if (lane == 0) sred[w] = sq;
    __syncthreads();
    if (threadIdx.x == 0) atomicAdd(&ssq[q], sred[0] + sred[1] + sred[2] + sred[3]);
}

// ---------------- outputs ----------------
__global__ void k_out0(const float* __restrict__ lat, const float* __restrict__ res2,
                       float* __restrict__ out) {
    int bi = blockIdx.x;            // b*512 + d
    int d = bi & 511, b = bi >> 9;
    const float* lp = lat + (size_t)bi * F_;
    const float* rp = res2 + (size_t)d * N_ + (size_t)b * F_;
    float* op = out + (size_t)bi * F_;
    for (int f = threadIdx.x; f < F_; f += 256) op[f] = lp[f] - rp[f];
}

__global__ void k_codes(const int* __restrict__ codes, float* __restrict__ out1) {
    int bi = blockIdx.x;            // b*8 + q
    int q = bi & 7, b = bi >> 3;
    for (int f = threadIdx.x; f < F_; f += 256)
        out1[(size_t)bi * F_ + f] = (float)codes[(size_t)q * N_ + (size_t)b * F_ + f];
}

__global__ void k_loss(const double* __restrict__ ssq, float* __restrict__ out2) {
    if (threadIdx.x == 0) {
        double s = 0;
        for (int q = 0; q < Q_; ++q) s += ssq[q];
        double val = s / ((double)Q_ * (double)B_ * (double)D_ * (double)F_);
        out2[0] = (float)val;   // commitment_loss
        out2[1] = (float)val;   // codebook_loss (numerically identical)
    }
}

extern "C" void kernel_launch(void* const* d_in, const int* in_sizes, int n_in,
                              void* d_out, int out_size, void* d_ws, size_t ws_size,
                              hipStream_t stream) {
    const float* lat = (const float*)d_in[0];   // [16,512,1500] fp32
    const float* cb  = (const float*)d_in[1];   // [8,1024,512]  fp32
    char* ws = (char*)d_ws;
    float*  res2  = (float*)(ws);                 // 49,152,000 B
    float*  cbT   = (float*)(ws + 49152000);      // 16,777,216 B
    int*    codes = (int*)  (ws + 65929216);      //    768,000 B
    float*  Hq    = (float*)(ws + 66697216);      //     32,768 B
    float*  Sn    = (float*)(ws + 66729984);      //     96,000 B
    double* ssq   = (double*)(ws + 66825984);     //         64 B
    float* out = (float*)d_out;

    hipLaunchKernelGGL(k_init,         dim3(B_ * D_), dim3(256), 0, stream, lat, res2, ssq);
    hipLaunchKernelGGL(k_transpose_cb, dim3(Q_ * 512), dim3(256), 0, stream, cb, cbT);
    hipLaunchKernelGGL(k_cbnormP,      dim3(Q_ * C_ / 256), dim3(256), 0, stream, cb, Hq);

    for (int q = 0; q < Q_; ++q) {
        hipLaunchKernelGGL(k_rownorm, dim3(NBLK), dim3(256), 0, stream, res2, Sn);
        hipLaunchKernelGGL(k_dist,    dim3(N_ / 32), dim3(256), 0, stream,
                           res2, cb, Hq, Sn, codes, q);
        hipLaunchKernelGGL(k_update,  dim3(D_ * NBLK), dim3(256), 0, stream,
                           res2, cbT, codes, ssq, q);
    }

    hipLaunchKernelGGL(k_out0,  dim3(B_ * D_), dim3(256), 0, stream, lat, res2, out);
    hipLaunchKernelGGL(k_codes, dim3(B_ * Q_), dim3(256), 0, stream, codes, out + 12288000);
    hipLaunchKernelGGL(k_loss,  dim3(1), dim3(64), 0, stream, ssq, out + 12480000);
}

// Round 6
// 4153.371 us; speedup vs baseline: 2.3132x; 2.3132x over previous
//
#include <hip/hip_runtime.h>

// ResidualVectorQuantizer: B=16, D=512, F=1500, Q=8, C=1024
#define B_ 16
#define D_ 512
#define F_ 1500
#define N_ (B_*F_)   // 24000
#define Q_ 8
#define C_ 1024

constexpr int NBLK  = (N_ + 255) / 256;   // 94
constexpr int UPDBLK = 4 * NBLK;          // 376 (4 d-segments of 128)

// ---------------- init: res2[d][b*F+f] = latents[b][d][f] ----------------
__global__ void k_init(const float* __restrict__ lat, float* __restrict__ res2) {
    int bi = blockIdx.x;            // bi = b*512 + d
    int d = bi & 511, b = bi >> 9;
    const float* src = lat + (size_t)bi * F_;
    float* dst = res2 + (size_t)d * N_ + (size_t)b * F_;
    for (int f = threadIdx.x; f < F_; f += 256) dst[f] = src[f];
}

// ---------------- codebook transpose: cbT[q][d][c] = cb[q][c][d] ----------------
__global__ void k_transpose_cb(const float* __restrict__ cb, float* __restrict__ cbT) {
    __shared__ float tile[32][33];
    int bi = blockIdx.x;            // q*512 + cblk*16 + dblk
    int q = bi >> 9;
    int rem = bi & 511;
    int cblk = rem >> 4, dblk = rem & 15;
    int tx = threadIdx.x & 31, ty = threadIdx.x >> 5;  // 32 x 8
    const float* src = cb + ((size_t)q * C_ + (size_t)cblk * 32) * D_ + dblk * 32;
    for (int i = ty; i < 32; i += 8) tile[i][tx] = src[(size_t)i * D_ + tx];
    __syncthreads();
    float* dst = cbT + ((size_t)q * D_ + (size_t)dblk * 32) * C_ + cblk * 32;
    for (int i = ty; i < 32; i += 8) dst[(size_t)i * C_ + tx] = tile[tx][i];
}

// ---------------- H[q*C+c] = np.sum(cb*cb, axis=1), numpy pairwise fp32 ----------------
__global__ void k_cbnormP(const float* __restrict__ cb, float* __restrict__ Hq) {
#pragma clang fp contract(off)
    int wid = blockIdx.x * 256 + threadIdx.x;   // q*C + c
    const float* p = cb + (size_t)wid * D_;
    float L[4];
#pragma unroll
    for (int l = 0; l < 4; ++l) {
        const float* pl = p + l * 128;
        float r[8];
#pragma unroll
        for (int j = 0; j < 8; ++j) { float x = pl[j]; r[j] = x * x; }
        for (int i = 8; i < 128; i += 8) {
#pragma unroll
            for (int j = 0; j < 8; ++j) { float x = pl[i + j]; r[j] = r[j] + x * x; }
        }
        L[l] = ((r[0] + r[1]) + (r[2] + r[3])) + ((r[4] + r[5]) + (r[6] + r[7]));
    }
    Hq[wid] = (L[0] + L[1]) + (L[2] + L[3]);
}

// ---------------- initial S partials (pairwise leaves of 128): Sp[l][n] ----------------
__global__ void k_rownorm4(const float* __restrict__ res2, float* __restrict__ Sp) {
#pragma clang fp contract(off)
    int n = blockIdx.x * 256 + threadIdx.x;
    if (n >= N_) return;
#pragma unroll
    for (int l = 0; l < 4; ++l) {
        const float* p = res2 + (size_t)(l * 128) * N_ + n;
        float r[8];
#pragma unroll
        for (int j = 0; j < 8; ++j) { float x = p[(size_t)j * N_]; r[j] = x * x; }
        for (int i = 8; i < 128; i += 8) {
#pragma unroll
            for (int j = 0; j < 8; ++j) { float x = p[(size_t)(i + j) * N_]; r[j] = r[j] + x * x; }
        }
        Sp[(size_t)l * N_ + n] = ((r[0] + r[1]) + (r[2] + r[3])) + ((r[4] + r[5]) + (r[6] + r[7]));
    }
}

// ---------------- distance + argmin, fp32, single sequential FMA chain (verified) ----------------
// block: 256 threads, 32 rows x 1024 cols; per-thread 2 rows x 8 cols.
__global__ __launch_bounds__(256) void k_dist(
        const float* __restrict__ res2, const float* __restrict__ cb,
        const float* __restrict__ Hq, const float* __restrict__ Sp,
        int* __restrict__ codes, int q) {
    __shared__ float xs[32][66];     // [n][d-chunk]
    __shared__ float cs[128][66];    // [c][d-chunk]
    __shared__ float redv[16][32];
    __shared__ int   redi[16][32];

    const int t = threadIdx.x;
    const int n0 = blockIdx.x * 32;
    const int tr = t & 15, tc = t >> 4;
    const float* cbq = cb + (size_t)q * ((size_t)C_ * D_);
    const float* Hqq = Hq + (size_t)q * C_;

    float S0, S1;
    {
#pragma clang fp contract(off)
        int na = n0 + 2 * tr, nb2 = na + 1;
        S0 = (Sp[na]  + Sp[N_ + na])  + (Sp[2 * N_ + na]  + Sp[3 * N_ + na]);
        S1 = (Sp[nb2] + Sp[N_ + nb2]) + (Sp[2 * N_ + nb2] + Sp[3 * N_ + nb2]);
    }

    float bestv0 = 3.4e38f, bestv1 = 3.4e38f;
    int besti0 = 0, besti1 = 0;

    for (int c0 = 0; c0 < C_; c0 += 128) {
        float acc[2][8] = {{0,0,0,0,0,0,0,0},{0,0,0,0,0,0,0,0}};

        for (int dc = 0; dc < D_; dc += 64) {
            __syncthreads();
            {   // stage X: 32 rows x 64 d
                int j = t & 31, dd0 = t >> 5;
#pragma unroll
                for (int k = 0; k < 8; ++k) {
                    int dd = dd0 + 8 * k;
                    xs[j][dd] = res2[(size_t)(dc + dd) * N_ + n0 + j];
                }
            }
            {   // stage CB: 128 rows x 64 d (float2)
#pragma unroll
                for (int k = 0; k < 16; ++k) {
                    int idx = t + k * 256;          // 0..4095
                    int r = idx >> 5;               // 0..127
                    int d2 = idx & 31;
                    const float2 v = *(const float2*)(cbq + (size_t)(c0 + r) * D_ + dc + 2 * d2);
                    *(float2*)(&cs[r][2 * d2]) = v;
                }
            }
            __syncthreads();

            const float2* xp0 = (const float2*)(&xs[2 * tr][0]);
            const float2* xp1 = (const float2*)(&xs[2 * tr + 1][0]);
            const float2* cp0 = (const float2*)(&cs[8 * tc + 0][0]);
            const float2* cp1 = (const float2*)(&cs[8 * tc + 1][0]);
            const float2* cp2 = (const float2*)(&cs[8 * tc + 2][0]);
            const float2* cp3 = (const float2*)(&cs[8 * tc + 3][0]);
            const float2* cp4 = (const float2*)(&cs[8 * tc + 4][0]);
            const float2* cp5 = (const float2*)(&cs[8 * tc + 5][0]);
            const float2* cp6 = (const float2*)(&cs[8 * tc + 6][0]);
            const float2* cp7 = (const float2*)(&cs[8 * tc + 7][0]);
#pragma unroll 4
            for (int d2 = 0; d2 < 32; ++d2) {
                const float2 x0 = xp0[d2], x1 = xp1[d2];
                // strict d-ascending fused-FMA chain per cell (verified exact)
#define STEP(K, CP) { const float2 cv = CP[d2]; \
                acc[0][K] = fmaf(x0.x, cv.x, acc[0][K]); acc[0][K] = fmaf(x0.y, cv.y, acc[0][K]); \
                acc[1][K] = fmaf(x1.x, cv.x, acc[1][K]); acc[1][K] = fmaf(x1.y, cv.y, acc[1][K]); }
                STEP(0, cp0) STEP(1, cp1) STEP(2, cp2) STEP(3, cp3)
                STEP(4, cp4) STEP(5, cp5) STEP(6, cp6) STEP(7, cp7)
#undef STEP
            }
        }

        {   // dist = fl(fl(S - 2A) + H), fp32; ties -> lowest index
#pragma clang fp contract(off)
#pragma unroll
            for (int k = 0; k < 8; ++k) {
                int c = c0 + 8 * tc + k;
                float h = Hqq[c];
                float t0 = S0 - 2.0f * acc[0][k];
                float t1 = S1 - 2.0f * acc[1][k];
                float v0 = t0 + h;
                float v1 = t1 + h;
                if (v0 < bestv0) { bestv0 = v0; besti0 = c; }
                if (v1 < bestv1) { bestv1 = v1; besti1 = c; }
            }
        }
    }

    redv[tc][2 * tr] = bestv0;     redi[tc][2 * tr] = besti0;
    redv[tc][2 * tr + 1] = bestv1; redi[tc][2 * tr + 1] = besti1;
    __syncthreads();
    if (t < 32) {
        float bv = redv[0][t]; int bidx = redi[0][t];
#pragma unroll
        for (int j = 1; j < 16; ++j) {
            float v = redv[j][t]; int ci = redi[j][t];
            if (v < bv || (v == bv && ci < bidx)) { bv = v; bidx = ci; }
        }
        codes[(size_t)q * N_ + n0 + t] = bidx;
    }
}

// ---------------- fused residual update + next-stage S partials + loss partials ----------------
// grid: 4 d-segments (128 d each = numpy pairwise leaf) x 94 n-blocks. No atomics.
__global__ __launch_bounds__(256) void k_upd(
        float* __restrict__ res2, const float* __restrict__ cbT,
        const int* __restrict__ codes, float* __restrict__ Sp,
        double* __restrict__ part, int q) {
#pragma clang fp contract(off)
    int seg = blockIdx.x / NBLK;          // 0..3
    int nb  = blockIdx.x % NBLK;
    int n = nb * 256 + threadIdx.x;
    float L = 0.0f;
    if (n < N_) {
        int idx = codes[(size_t)q * N_ + n];
        const float* crow = cbT + ((size_t)(q * 512 + seg * 128)) * C_ + idx;
        float* rp = res2 + (size_t)(seg * 128) * N_ + n;
        float r8[8];
#pragma unroll
        for (int j = 0; j < 8; ++j) {
            float r = rp[(size_t)j * N_] - crow[(size_t)j * C_];
            rp[(size_t)j * N_] = r;
            r8[j] = r * r;
        }
        for (int i = 8; i < 128; i += 8) {
#pragma unroll
            for (int j = 0; j < 8; ++j) {
                float r = rp[(size_t)(i + j) * N_] - crow[(size_t)(i + j) * C_];
                rp[(size_t)(i + j) * N_] = r;
                r8[j] = r8[j] + r * r;
            }
        }
        L = ((r8[0] + r8[1]) + (r8[2] + r8[3])) + ((r8[4] + r8[5]) + (r8[6] + r8[7]));
        Sp[(size_t)seg * N_ + n] = L;
    }
    // block-reduce sum of L into deterministic per-block partial (for the losses)
    double s = (double)L;
#pragma unroll
    for (int off = 32; off; off >>= 1) s += __shfl_down(s, off, 64);
    __shared__ double sred[4];
    int lane = threadIdx.x & 63, w = threadIdx.x >> 6;
    if (lane == 0) sred[w] = s;
    __syncthreads();
    if (threadIdx.x == 0)
        part[(size_t)q * UPDBLK + blockIdx.x] = sred[0] + sred[1] + sred[2] + sred[3];
}

// ---------------- outputs ----------------
__global__ void k_out0(const float* __restrict__ lat, const float* __restrict__ res2,
                       float* __restrict__ out) {
    int bi = blockIdx.x;            // b*512 + d
    int d = bi & 511, b = bi >> 9;
    const float* lp = lat + (size_t)bi * F_;
    const float* rp = res2 + (size_t)d * N_ + (size_t)b * F_;
    float* op = out + (size_t)bi * F_;
    for (int f = threadIdx.x; f < F_; f += 256) op[f] = lp[f] - rp[f];
}

__global__ void k_codes(const int* __restrict__ codes, float* __restrict__ out1) {
    int bi = blockIdx.x;            // b*8 + q
    int q = bi & 7, b = bi >> 3;
    for (int f = threadIdx.x; f < F_; f += 256)
        out1[(size_t)bi * F_ + f] = (float)codes[(size_t)q * N_ + (size_t)b * F_ + f];
}

__global__ void k_loss(const double* __restrict__ part, float* __restrict__ out2) {
    double s = 0.0;
    for (int i = threadIdx.x; i < Q_ * UPDBLK; i += 256) s += part[i];
#pragma unroll
    for (int off = 32; off; off >>= 1) s += __shfl_down(s, off, 64);
    __shared__ double red[4];
    int lane = threadIdx.x & 63, w = threadIdx.x >> 6;
    if (lane == 0) red[w] = s;
    __syncthreads();
    if (threadIdx.x == 0) {
        double tot = red[0] + red[1] + red[2] + red[3];
        float val = (float)(tot / ((double)Q_ * (double)B_ * (double)D_ * (double)F_));
        out2[0] = val;   // commitment_loss
        out2[1] = val;   // codebook_loss (numerically identical)
    }
}

extern "C" void kernel_launch(void* const* d_in, const int* in_sizes, int n_in,
                              void* d_out, int out_size, void* d_ws, size_t ws_size,
                              hipStream_t stream) {
    const float* lat = (const float*)d_in[0];   // [16,512,1500] fp32
    const float* cb  = (const float*)d_in[1];   // [8,1024,512]  fp32
    char* ws = (char*)d_ws;
    float*  res2  = (float*)(ws);                 // 49,152,000 B
    float*  cbT   = (float*)(ws + 49152000);      // 16,777,216 B
    int*    codes = (int*)  (ws + 65929216);      //    768,000 B
    float*  Hq    = (float*)(ws + 66697216);      //     32,768 B
    float*  Sp    = (float*)(ws + 66729984);      //    384,000 B (4 x 24000 f32)
    double* part  = (double*)(ws + 67113984);     //     24,064 B (8 x 376 f64)
    float* out = (float*)d_out;

    hipLaunchKernelGGL(k_init,         dim3(B_ * D_), dim3(256), 0, stream, lat, res2);
    hipLaunchKernelGGL(k_transpose_cb, dim3(Q_ * 512), dim3(256), 0, stream, cb, cbT);
    hipLaunchKernelGGL(k_cbnormP,      dim3(Q_ * C_ / 256), dim3(256), 0, stream, cb, Hq);
    hipLaunchKernelGGL(k_rownorm4,     dim3(NBLK), dim3(256), 0, stream, res2, Sp);

    for (int q = 0; q < Q_; ++q) {
        hipLaunchKernelGGL(k_dist, dim3(N_ / 32), dim3(256), 0, stream,
                           res2, cb, Hq, Sp, codes, q);
        hipLaunchKernelGGL(k_upd,  dim3(UPDBLK), dim3(256), 0, stream,
                           res2, cbT, codes, Sp, part, q);
    }

    hipLaunchKernelGGL(k_out0,  dim3(B_ * D_), dim3(256), 0, stream, lat, res2, out);
    hipLaunchKernelGGL(k_codes, dim3(B_ * Q_), dim3(256), 0, stream, codes, out + 12288000);
    hipLaunchKernelGGL(k_loss,  dim3(1), dim3(256), 0, stream, part, out + 12480000);
}